// Round 2
// baseline (141.532 us; speedup 1.0000x reference)
//
#include <hip/hip_runtime.h>

typedef float    f32x4 __attribute__((ext_vector_type(4)));
typedef _Float16 h16x8 __attribute__((ext_vector_type(8)));

#define NB 32
#define NS 1024
#define ND 256
#define NEGINF (-4.2949673e9f)

__device__ __forceinline__ f32x4 mfmah(h16x8 a, h16x8 b, f32x4 c) {
    return __builtin_amdgcn_mfma_f32_16x16x32_f16(a, b, c, 0, 0, 0);
}

template <typename T>
__device__ __forceinline__ void gload16(const T* g, void* l) {
    __builtin_amdgcn_global_load_lds(
        (const __attribute__((address_space(1))) void*)g,
        (__attribute__((address_space(3))) void*)l, 16, 0, 0);
}

// ---------------- K0: pe table (f32) + W^T split into hi/lo fp16 ----------------
__global__ void setup_kernel(const float* __restrict__ W, float* __restrict__ pe,
                             _Float16* __restrict__ wth, _Float16* __restrict__ wtl) {
    int t = threadIdx.x;
    int bid = blockIdx.x;
    if (bid < 1024) {
        int s = bid, d = t;
        float f = __builtin_exp2f(-(float)(d >> 1) * 0.10381025296523007f);
        float ang = (float)s * f;
        pe[s * ND + d] = (d & 1) ? cosf(ang) : sinf(ang);
    } else {
        int idx = (bid - 1024) * 256 + t;   // 65536 elems
        int n = idx >> 8, d = idx & 255;
        float w = W[(size_t)d * ND + n];
        _Float16 h = (_Float16)w;
        wth[(size_t)n * ND + d] = h;
        wtl[(size_t)n * ND + d] = (_Float16)(w - (float)h);
    }
}

// ---------------- K1: Qp/Kp = relu((x+pe)W), split-fp16 GEMM ----------------
// M = 65536 rows (q then k), N = 256, K = 256. BM=128, BN=128, BK=32, 4 waves.
__global__ __launch_bounds__(256, 2) void proj_kernel(
    const float* __restrict__ q, const float* __restrict__ k,
    const float* __restrict__ pe,
    const _Float16* __restrict__ wth, const _Float16* __restrict__ wtl,
    _Float16* __restrict__ qph, _Float16* __restrict__ qpl,
    _Float16* __restrict__ kph, _Float16* __restrict__ kpl) {
    __shared__ __align__(16) _Float16 lah[128][40];
    __shared__ __align__(16) _Float16 lal[128][40];
    __shared__ __align__(16) _Float16 lbh[128][40];
    __shared__ __align__(16) _Float16 lbl[128][40];
    int t = threadIdx.x;
    int bm = blockIdx.x >> 1, bn = blockIdx.x & 1;
    int lane = t & 63, wid = t >> 6;
    int wm = wid >> 1, wn = wid & 1;
    int lr = lane & 15, lg = lane >> 4;

    f32x4 acc[4][4];
    #pragma unroll
    for (int i = 0; i < 4; ++i)
        #pragma unroll
        for (int j = 0; j < 4; ++j) acc[i][j] = (f32x4){0.f, 0.f, 0.f, 0.f};

    for (int kk = 0; kk < 8; ++kk) {
        // ---- stage A: 128 rows x 32 cols, f32 -> (hi,lo) fp16 ----
        #pragma unroll
        for (int it = 0; it < 2; ++it) {
            int gi = it * 256 + t;          // 512 granules of 8 floats
            int r = gi >> 2, qtr = gi & 3;
            long grow = (long)bm * 128 + r;
            const float* srcRow = (grow < 32768) ? (q + grow * ND)
                                                 : (k + (grow - 32768) * ND);
            const float* peRow = pe + (grow & 1023) * ND;
            int db = kk * 32 + qtr * 8;
            float4 x0 = *(const float4*)(srcRow + db);
            float4 x1 = *(const float4*)(srcRow + db + 4);
            float4 p0 = *(const float4*)(peRow + db);
            float4 p1 = *(const float4*)(peRow + db + 4);
            float s[8] = {x0.x + p0.x, x0.y + p0.y, x0.z + p0.z, x0.w + p0.w,
                          x1.x + p1.x, x1.y + p1.y, x1.z + p1.z, x1.w + p1.w};
            h16x8 oh, ol;
            #pragma unroll
            for (int j = 0; j < 8; ++j) {
                _Float16 h = (_Float16)s[j];
                oh[j] = h;
                ol[j] = (_Float16)(s[j] - (float)h);
            }
            *(h16x8*)&lah[r][qtr * 8] = oh;
            *(h16x8*)&lal[r][qtr * 8] = ol;
        }
        // ---- stage B: Wt hi/lo tiles 128 x 32 ----
        #pragma unroll
        for (int it = 0; it < 2; ++it) {
            int gi = it * 256 + t;
            int r = gi >> 2, qtr = gi & 3;
            int nrow = bn * 128 + r;
            size_t off = (size_t)nrow * ND + kk * 32 + qtr * 8;
            *(uint4*)&lbh[r][qtr * 8] = *(const uint4*)(wth + off);
            *(uint4*)&lbl[r][qtr * 8] = *(const uint4*)(wtl + off);
        }
        __syncthreads();
        h16x8 afh[4], afl[4], bvh[4], bvl[4];
        #pragma unroll
        for (int i = 0; i < 4; ++i) {
            afh[i] = *(const h16x8*)&lah[wm * 64 + i * 16 + lr][lg * 8];
            afl[i] = *(const h16x8*)&lal[wm * 64 + i * 16 + lr][lg * 8];
        }
        #pragma unroll
        for (int j = 0; j < 4; ++j) {
            bvh[j] = *(const h16x8*)&lbh[wn * 64 + j * 16 + lr][lg * 8];
            bvl[j] = *(const h16x8*)&lbl[wn * 64 + j * 16 + lr][lg * 8];
        }
        #pragma unroll
        for (int i = 0; i < 4; ++i)
            #pragma unroll
            for (int j = 0; j < 4; ++j) {
                acc[i][j] = mfmah(afh[i], bvh[j], acc[i][j]);
                acc[i][j] = mfmah(afh[i], bvl[j], acc[i][j]);
                acc[i][j] = mfmah(afl[i], bvh[j], acc[i][j]);
            }
        __syncthreads();
    }
    // ---- epilogue: relu -> split fp16 -> Qp/Kp hi,lo ----
    long mbase = (long)bm * 128 + wm * 64;
    int nbase = bn * 128 + wn * 64;
    #pragma unroll
    for (int i = 0; i < 4; ++i) {
        #pragma unroll
        for (int jj = 0; jj < 4; ++jj) {
            long gr = mbase + i * 16 + lg * 4 + jj;
            _Float16* dsth = (gr < 32768) ? (qph + gr * ND) : (kph + (gr - 32768) * ND);
            _Float16* dstl = (gr < 32768) ? (qpl + gr * ND) : (kpl + (gr - 32768) * ND);
            #pragma unroll
            for (int j = 0; j < 4; ++j) {
                float val = acc[i][j][jj];
                val = val > 0.0f ? val : 0.0f;
                _Float16 h = (_Float16)val;
                dsth[nbase + j * 16 + lr] = h;
                dstl[nbase + j * 16 + lr] = (_Float16)(val - (float)h);
            }
        }
    }
}

// ---------------- K2: attention column-weights (split-fp16 QK^T) ----------------
// grid = 32 b * 32 qt. 4 waves; wave w owns k cols {c*64 + w*16 + 0..15}.
__global__ __launch_bounds__(256, 2) void attn_kernel(
    const _Float16* __restrict__ qph, const _Float16* __restrict__ qpl,
    const _Float16* __restrict__ kph, const _Float16* __restrict__ kpl,
    const int* __restrict__ mask, float* __restrict__ w_part) {
    __shared__ __align__(16) char smem[70656];
    _Float16* kbuf  = (_Float16*)smem;             // [64][256] swizzled (reused hi/lo)
    _Float16* qhbuf = (_Float16*)(smem + 32768);   // [32][256] swizzled
    _Float16* qlbuf = (_Float16*)(smem + 49152);   // [32][256] swizzled
    int*   mbuf = (int*)(smem + 65536);            // [1024]
    float* redm = (float*)(smem + 69632);          // [4][32]
    float* redz = redm + 128;                      // [4][32]

    int t = threadIdx.x, lane = t & 63, wid = t >> 6;
    int lr = lane & 15, lg = lane >> 4;
    int b = blockIdx.x >> 5, qt = blockIdx.x & 31;
    const _Float16* qph_b = qph + ((size_t)(b * 1024 + qt * 32)) * ND;
    const _Float16* qpl_b = qpl + ((size_t)(b * 1024 + qt * 32)) * ND;
    const _Float16* kph_b = kph + ((size_t)b * 1024) * ND;
    const _Float16* kpl_b = kpl + ((size_t)b * 1024) * ND;

    // stage Q hi/lo tiles + mask; swizzle granule g -> g ^ (row&7)
    #pragma unroll
    for (int it = 0; it < 4; ++it) {
        int gi = it * 256 + t, kl = gi >> 5, g = gi & 31;
        gload16(qph_b + (size_t)kl * ND + ((g ^ (kl & 7)) << 3), (char*)qhbuf + gi * 16);
    }
    #pragma unroll
    for (int it = 0; it < 4; ++it) {
        int gi = it * 256 + t, kl = gi >> 5, g = gi & 31;
        gload16(qpl_b + (size_t)kl * ND + ((g ^ (kl & 7)) << 3), (char*)qlbuf + gi * 16);
    }
    gload16(mask + (size_t)b * 1024 + t * 4, (char*)mbuf + t * 16);
    __syncthreads();

    // hoist Q-hi fragments to registers (rows lr and lr+16, all 8 k-slices)
    h16x8 q0h[8], q1h[8];
    #pragma unroll
    for (int ds = 0; ds < 8; ++ds) {
        int gA = ds * 4 + lg;
        q0h[ds] = *(const h16x8*)((char*)qhbuf + lr * 512 + ((gA ^ (lr & 7)) << 4));
        q1h[ds] = *(const h16x8*)((char*)qhbuf + (16 + lr) * 512 + ((gA ^ (lr & 7)) << 4));
    }

    f32x4 p[16][2];
    int krow = wid * 16 + lr;
    #pragma unroll
    for (int c = 0; c < 16; ++c) {
        // ---- stage K-hi chunk ----
        #pragma unroll
        for (int it = 0; it < 8; ++it) {
            int gi = it * 256 + t, kl = gi >> 5, g = gi & 31;
            gload16(kph_b + (size_t)(c * 64 + kl) * ND + ((g ^ (kl & 7)) << 3),
                    (char*)kbuf + gi * 16);
        }
        __syncthreads();
        f32x4 a0 = {0.f, 0.f, 0.f, 0.f}, a1 = {0.f, 0.f, 0.f, 0.f};
        #pragma unroll
        for (int ds = 0; ds < 8; ++ds) {
            int gA = ds * 4 + lg;
            h16x8 bh = *(const h16x8*)((char*)kbuf + krow * 512 + ((gA ^ (krow & 7)) << 4));
            h16x8 l0 = *(const h16x8*)((char*)qlbuf + lr * 512 + ((gA ^ (lr & 7)) << 4));
            h16x8 l1 = *(const h16x8*)((char*)qlbuf + (16 + lr) * 512 + ((gA ^ (lr & 7)) << 4));
            a0 = mfmah(q0h[ds], bh, a0);
            a0 = mfmah(l0, bh, a0);
            a1 = mfmah(q1h[ds], bh, a1);
            a1 = mfmah(l1, bh, a1);
        }
        __syncthreads();
        // ---- stage K-lo chunk (same buffer) ----
        #pragma unroll
        for (int it = 0; it < 8; ++it) {
            int gi = it * 256 + t, kl = gi >> 5, g = gi & 31;
            gload16(kpl_b + (size_t)(c * 64 + kl) * ND + ((g ^ (kl & 7)) << 3),
                    (char*)kbuf + gi * 16);
        }
        __syncthreads();
        #pragma unroll
        for (int ds = 0; ds < 8; ++ds) {
            int gA = ds * 4 + lg;
            h16x8 bl = *(const h16x8*)((char*)kbuf + krow * 512 + ((gA ^ (krow & 7)) << 4));
            a0 = mfmah(q0h[ds], bl, a0);
            a1 = mfmah(q1h[ds], bl, a1);
        }
        p[c][0] = a0; p[c][1] = a1;
        __syncthreads();
    }

    // ---- softmax over k (rows = q), then column sums ----
    int mv[16];
    #pragma unroll
    for (int c = 0; c < 16; ++c) mv[c] = mbuf[c * 64 + wid * 16 + lr];
    #pragma unroll
    for (int c = 0; c < 16; ++c)
        #pragma unroll
        for (int qf = 0; qf < 2; ++qf)
            #pragma unroll
            for (int j = 0; j < 4; ++j) {
                float val = p[c][qf][j] * 0.0625f;   // / sqrt(256)
                p[c][qf][j] = (mv[c] != 0) ? val : NEGINF;
            }
    float mrow[2][4];
    #pragma unroll
    for (int qf = 0; qf < 2; ++qf)
        #pragma unroll
        for (int j = 0; j < 4; ++j) {
            float m = -3.4e38f;
            #pragma unroll
            for (int c = 0; c < 16; ++c) m = fmaxf(m, p[c][qf][j]);
            #pragma unroll
            for (int d = 1; d < 16; d <<= 1) m = fmaxf(m, __shfl_xor(m, d));
            mrow[qf][j] = m;
        }
    if (lr == 0) {
        #pragma unroll
        for (int qf = 0; qf < 2; ++qf)
            #pragma unroll
            for (int j = 0; j < 4; ++j)
                redm[wid * 32 + qf * 16 + lg * 4 + j] = mrow[qf][j];
    }
    __syncthreads();
    float mf[2][4];
    #pragma unroll
    for (int qf = 0; qf < 2; ++qf)
        #pragma unroll
        for (int j = 0; j < 4; ++j) {
            int row = qf * 16 + lg * 4 + j;
            mf[qf][j] = fmaxf(fmaxf(redm[row], redm[32 + row]),
                              fmaxf(redm[64 + row], redm[96 + row]));
        }
    float zp[2][4] = {{0.f,0.f,0.f,0.f},{0.f,0.f,0.f,0.f}};
    #pragma unroll
    for (int c = 0; c < 16; ++c)
        #pragma unroll
        for (int qf = 0; qf < 2; ++qf)
            #pragma unroll
            for (int j = 0; j < 4; ++j) {
                float e = __expf(p[c][qf][j] - mf[qf][j]);
                p[c][qf][j] = e;
                zp[qf][j] += e;
            }
    #pragma unroll
    for (int qf = 0; qf < 2; ++qf)
        #pragma unroll
        for (int j = 0; j < 4; ++j) {
            #pragma unroll
            for (int d = 1; d < 16; d <<= 1) zp[qf][j] += __shfl_xor(zp[qf][j], d);
        }
    if (lr == 0) {
        #pragma unroll
        for (int qf = 0; qf < 2; ++qf)
            #pragma unroll
            for (int j = 0; j < 4; ++j)
                redz[wid * 32 + qf * 16 + lg * 4 + j] = zp[qf][j];
    }
    __syncthreads();
    float rz[2][4];
    #pragma unroll
    for (int qf = 0; qf < 2; ++qf)
        #pragma unroll
        for (int j = 0; j < 4; ++j) {
            int row = qf * 16 + lg * 4 + j;
            float z = redz[row] + redz[32 + row] + redz[64 + row] + redz[96 + row];
            rz[qf][j] = 1.0f / z;
        }
    float* wp = w_part + ((size_t)(b * 32 + qt)) * 1024;
    #pragma unroll
    for (int c = 0; c < 16; ++c) {
        float cs = 0.f;
        #pragma unroll
        for (int qf = 0; qf < 2; ++qf)
            #pragma unroll
            for (int j = 0; j < 4; ++j)
                cs = fmaf(p[c][qf][j], rz[qf][j], cs);
        cs += __shfl_xor(cs, 16);
        cs += __shfl_xor(cs, 32);
        if (lane < 16) wp[c * 64 + wid * 16 + lane] = cs;
    }
}

// ---------------- K3: out[b,d] = (1/S) * sum_k w[b,k] * v[b,k,d] ----------------
__global__ void zero_out_kernel(float* __restrict__ out) {
    out[blockIdx.x * 256 + threadIdx.x] = 0.0f;
}

__global__ __launch_bounds__(256) void pv_kernel(
    const float* __restrict__ w_part, const float* __restrict__ v,
    float* __restrict__ out) {
    __shared__ float wseg[128];
    int t = threadIdx.x;
    int b = blockIdx.x >> 3, ks = blockIdx.x & 7;
    if (t < 128) {
        float s = 0.f;
        #pragma unroll 8
        for (int qt = 0; qt < 32; ++qt)
            s += w_part[((size_t)(b * 32 + qt)) * 1024 + ks * 128 + t];
        wseg[t] = s;
    }
    __syncthreads();
    const float* vb = v + ((size_t)b * 1024 + ks * 128) * ND + t;
    float acc = 0.f;
    #pragma unroll 8
    for (int kk = 0; kk < 128; ++kk)
        acc = fmaf(wseg[kk], vb[(size_t)kk * ND], acc);
    atomicAdd(out + b * 256 + t, acc * (1.0f / 1024.0f));
}

extern "C" void kernel_launch(void* const* d_in, const int* in_sizes, int n_in,
                              void* d_out, int out_size, void* d_ws, size_t ws_size,
                              hipStream_t stream) {
    const float* q = (const float*)d_in[0];
    const float* k = (const float*)d_in[1];
    const float* v = (const float*)d_in[2];
    const int* mask = (const int*)d_in[3];
    const float* W = (const float*)d_in[4];
    char* ws = (char*)d_ws;
    float*    pe  = (float*)ws;                                   // 1 MB
    _Float16* wth = (_Float16*)(ws + 1048576);                    // 128 KB
    _Float16* wtl = (_Float16*)(ws + 1048576 + 131072);           // 128 KB
    _Float16* qph = (_Float16*)(ws + 1310720);                    // 16 MB
    _Float16* qpl = (_Float16*)(ws + 1310720 + 16777216);         // 16 MB
    _Float16* kph = (_Float16*)(ws + 1310720 + 2*16777216);      // 16 MB
    _Float16* kpl = (_Float16*)(ws + 1310720 + 3*16777216);      // 16 MB
    float* wpart  = (float*)(ws + 1310720 + 4*16777216);         // 4 MB
    float* out = (float*)d_out;

    setup_kernel<<<1280, 256, 0, stream>>>(W, pe, wth, wtl);
    proj_kernel<<<1024, 256, 0, stream>>>(q, k, pe, wth, wtl, qph, qpl, kph, kpl);
    attn_kernel<<<1024, 256, 0, stream>>>(qph, qpl, kph, kpl, mask, wpart);
    zero_out_kernel<<<32, 256, 0, stream>>>(out);
    pv_kernel<<<256, 256, 0, stream>>>(wpart, v, out);
}

// Round 3
// 137.541 us; speedup vs baseline: 1.0290x; 1.0290x over previous
//
#include <hip/hip_runtime.h>

typedef float    f32x4 __attribute__((ext_vector_type(4)));
typedef _Float16 h16x8 __attribute__((ext_vector_type(8)));

#define NB 32
#define NS 1024
#define ND 256
#define NEGINF (-4.2949673e9f)

__device__ __forceinline__ f32x4 mfmah(h16x8 a, h16x8 b, f32x4 c) {
    return __builtin_amdgcn_mfma_f32_16x16x32_f16(a, b, c, 0, 0, 0);
}

template <typename T>
__device__ __forceinline__ void gload16(const T* g, void* l) {
    __builtin_amdgcn_global_load_lds(
        (const __attribute__((address_space(1))) void*)g,
        (__attribute__((address_space(3))) void*)l, 16, 0, 0);
}

// ---------------- K0: pe table (f32) + W^T split into hi/lo fp16 ----------------
__global__ void setup_kernel(const float* __restrict__ W, float* __restrict__ pe,
                             _Float16* __restrict__ wth, _Float16* __restrict__ wtl) {
    int t = threadIdx.x;
    int bid = blockIdx.x;
    if (bid < 1024) {
        int s = bid, d = t;
        float f = __builtin_exp2f(-(float)(d >> 1) * 0.10381025296523007f);
        float ang = (float)s * f;
        pe[s * ND + d] = (d & 1) ? cosf(ang) : sinf(ang);
    } else {
        int idx = (bid - 1024) * 256 + t;   // 65536 elems
        int n = idx >> 8, d = idx & 255;
        float w = W[(size_t)d * ND + n];
        _Float16 h = (_Float16)w;
        wth[(size_t)n * ND + d] = h;
        wtl[(size_t)n * ND + d] = (_Float16)(w - (float)h);
    }
}

// ---------------- K1: Qp/Kp = relu((x+pe)W), split-fp16 GEMM ----------------
// M = 65536 rows (q then k), N = 256, K = 256. BM=128, BN=128, BK=32, 4 waves.
__global__ __launch_bounds__(256, 2) void proj_kernel(
    const float* __restrict__ q, const float* __restrict__ k,
    const float* __restrict__ pe,
    const _Float16* __restrict__ wth, const _Float16* __restrict__ wtl,
    _Float16* __restrict__ qph, _Float16* __restrict__ qpl,
    _Float16* __restrict__ kph, _Float16* __restrict__ kpl) {
    __shared__ __align__(16) _Float16 lah[128][40];
    __shared__ __align__(16) _Float16 lal[128][40];
    __shared__ __align__(16) _Float16 lbh[128][40];
    __shared__ __align__(16) _Float16 lbl[128][40];
    int t = threadIdx.x;
    int bm = blockIdx.x >> 1, bn = blockIdx.x & 1;
    int lane = t & 63, wid = t >> 6;
    int wm = wid >> 1, wn = wid & 1;
    int lr = lane & 15, lg = lane >> 4;

    f32x4 acc[4][4];
    #pragma unroll
    for (int i = 0; i < 4; ++i)
        #pragma unroll
        for (int j = 0; j < 4; ++j) acc[i][j] = (f32x4){0.f, 0.f, 0.f, 0.f};

    for (int kk = 0; kk < 8; ++kk) {
        // ---- stage A: 128 rows x 32 cols, f32 -> (hi,lo) fp16 ----
        #pragma unroll
        for (int it = 0; it < 2; ++it) {
            int gi = it * 256 + t;          // 512 granules of 8 floats
            int r = gi >> 2, qtr = gi & 3;
            long grow = (long)bm * 128 + r;
            const float* srcRow = (grow < 32768) ? (q + grow * ND)
                                                 : (k + (grow - 32768) * ND);
            const float* peRow = pe + (grow & 1023) * ND;
            int db = kk * 32 + qtr * 8;
            float4 x0 = *(const float4*)(srcRow + db);
            float4 x1 = *(const float4*)(srcRow + db + 4);
            float4 p0 = *(const float4*)(peRow + db);
            float4 p1 = *(const float4*)(peRow + db + 4);
            float s[8] = {x0.x + p0.x, x0.y + p0.y, x0.z + p0.z, x0.w + p0.w,
                          x1.x + p1.x, x1.y + p1.y, x1.z + p1.z, x1.w + p1.w};
            h16x8 oh, ol;
            #pragma unroll
            for (int j = 0; j < 8; ++j) {
                _Float16 h = (_Float16)s[j];
                oh[j] = h;
                ol[j] = (_Float16)(s[j] - (float)h);
            }
            *(h16x8*)&lah[r][qtr * 8] = oh;
            *(h16x8*)&lal[r][qtr * 8] = ol;
        }
        // ---- stage B: Wt hi/lo tiles 128 x 32 ----
        #pragma unroll
        for (int it = 0; it < 2; ++it) {
            int gi = it * 256 + t;
            int r = gi >> 2, qtr = gi & 3;
            int nrow = bn * 128 + r;
            size_t off = (size_t)nrow * ND + kk * 32 + qtr * 8;
            *(uint4*)&lbh[r][qtr * 8] = *(const uint4*)(wth + off);
            *(uint4*)&lbl[r][qtr * 8] = *(const uint4*)(wtl + off);
        }
        __syncthreads();
        h16x8 afh[4], afl[4], bvh[4], bvl[4];
        #pragma unroll
        for (int i = 0; i < 4; ++i) {
            afh[i] = *(const h16x8*)&lah[wm * 64 + i * 16 + lr][lg * 8];
            afl[i] = *(const h16x8*)&lal[wm * 64 + i * 16 + lr][lg * 8];
        }
        #pragma unroll
        for (int j = 0; j < 4; ++j) {
            bvh[j] = *(const h16x8*)&lbh[wn * 64 + j * 16 + lr][lg * 8];
            bvl[j] = *(const h16x8*)&lbl[wn * 64 + j * 16 + lr][lg * 8];
        }
        #pragma unroll
        for (int i = 0; i < 4; ++i)
            #pragma unroll
            for (int j = 0; j < 4; ++j) {
                acc[i][j] = mfmah(afh[i], bvh[j], acc[i][j]);
                acc[i][j] = mfmah(afh[i], bvl[j], acc[i][j]);
                acc[i][j] = mfmah(afl[i], bvh[j], acc[i][j]);
            }
        __syncthreads();
    }
    // ---- epilogue: relu -> split fp16 -> Qp/Kp hi,lo ----
    long mbase = (long)bm * 128 + wm * 64;
    int nbase = bn * 128 + wn * 64;
    #pragma unroll
    for (int i = 0; i < 4; ++i) {
        #pragma unroll
        for (int jj = 0; jj < 4; ++jj) {
            long gr = mbase + i * 16 + lg * 4 + jj;
            _Float16* dsth = (gr < 32768) ? (qph + gr * ND) : (kph + (gr - 32768) * ND);
            _Float16* dstl = (gr < 32768) ? (qpl + gr * ND) : (kpl + (gr - 32768) * ND);
            #pragma unroll
            for (int j = 0; j < 4; ++j) {
                float val = acc[i][j][jj];
                val = val > 0.0f ? val : 0.0f;
                _Float16 h = (_Float16)val;
                dsth[nbase + j * 16 + lr] = h;
                dstl[nbase + j * 16 + lr] = (_Float16)(val - (float)h);
            }
        }
    }
}

// ---------------- K2: attention column-weights (pipelined split-fp16 QK^T) ----
// grid = 1024, XCD-swizzled so each XCD owns 4 consecutive b's (K L2-resident).
// 32 half-chunk steps (hi/lo alternating, 64 k-rows each), 2-buffer ping-pong,
// counted vmcnt(8) so the next stage stays in flight across barriers.
__global__ __launch_bounds__(256, 2) void attn_kernel(
    const _Float16* __restrict__ qph, const _Float16* __restrict__ qpl,
    const _Float16* __restrict__ kph, const _Float16* __restrict__ kpl,
    const int* __restrict__ mask, float* __restrict__ w_part) {
    __shared__ __align__(16) char smem[81920];
    _Float16* kbuf0 = (_Float16*)smem;             // 32KB: hi steps (Q-hi staging first, red after)
    _Float16* kbuf1 = (_Float16*)(smem + 32768);   // 32KB: lo steps
    _Float16* qlbuf = (_Float16*)(smem + 65536);   // 16KB: Q-lo, resident
    float* redm = (float*)smem;                    // alias kbuf0 (used after K loop)
    float* redz = redm + 128;

    int t = threadIdx.x, lane = t & 63, wid = t >> 6;
    int lr = lane & 15, lg = lane >> 4;
    // XCD swizzle: 1024 wgs, 8 XCDs round-robin -> XCD x gets b in [4x, 4x+4)
    int wg = blockIdx.x;
    int swzb = (wg & 7) * 128 + (wg >> 3);
    int b = swzb >> 5, qt = swzb & 31;
    const _Float16* qph_b = qph + ((size_t)(b * 1024 + qt * 32)) * ND;
    const _Float16* qpl_b = qpl + ((size_t)(b * 1024 + qt * 32)) * ND;
    const _Float16* kph_b = kph + ((size_t)b * 1024) * ND;
    const _Float16* kpl_b = kpl + ((size_t)b * 1024) * ND;

    // P1: stage Q-hi (via kbuf0) and Q-lo (qlbuf); swizzle granule g -> g^(row&7)
    #pragma unroll
    for (int it = 0; it < 4; ++it) {
        int gi = it * 256 + t, kl = gi >> 5, g = gi & 31;
        gload16(qph_b + (size_t)kl * ND + ((g ^ (kl & 7)) << 3), (char*)kbuf0 + gi * 16);
        gload16(qpl_b + (size_t)kl * ND + ((g ^ (kl & 7)) << 3), (char*)qlbuf + gi * 16);
    }
    __syncthreads();
    // P2: hoist Q-hi fragments to regs; mask to regs
    h16x8 q0h[8], q1h[8];
    #pragma unroll
    for (int ds = 0; ds < 8; ++ds) {
        int gA = ds * 4 + lg;
        q0h[ds] = *(const h16x8*)((char*)kbuf0 + lr * 512 + ((gA ^ (lr & 7)) << 4));
        q1h[ds] = *(const h16x8*)((char*)kbuf0 + (16 + lr) * 512 + ((gA ^ (lr & 7)) << 4));
    }
    int mv[16];
    #pragma unroll
    for (int c = 0; c < 16; ++c)
        mv[c] = mask[(size_t)b * 1024 + c * 64 + wid * 16 + lr];
    __syncthreads();   // all Q-hi reads done (kbuf0 free), vmcnt drained
    // P3: stage step 0 (K-hi chunk 0) into kbuf0
    #pragma unroll
    for (int it = 0; it < 8; ++it) {
        int gi = it * 256 + t, kl = gi >> 5, g = gi & 31;
        gload16(kph_b + (size_t)kl * ND + ((g ^ (kl & 7)) << 3), (char*)kbuf0 + gi * 16);
    }
    __syncthreads();   // step 0 resident

    f32x4 p[16][2];
    f32x4 acc0, acc1;
    int krow = wid * 16 + lr;
    #pragma unroll
    for (int s = 0; s < 32; ++s) {
        // issue stage of step s+1 into the buffer not being read this step
        if (s < 31) {
            int c1 = (s + 1) >> 1;
            const _Float16* src = ((s + 1) & 1) ? kpl_b : kph_b;
            char* dst = ((s + 1) & 1) ? (char*)kbuf1 : (char*)kbuf0;
            #pragma unroll
            for (int it = 0; it < 8; ++it) {
                int gi = it * 256 + t, kl = gi >> 5, g = gi & 31;
                gload16(src + (size_t)(c1 * 64 + kl) * ND + ((g ^ (kl & 7)) << 3),
                        dst + gi * 16);
            }
            asm volatile("s_waitcnt vmcnt(8)" ::: "memory");  // step s resident, s+1 in flight
        } else {
            asm volatile("s_waitcnt vmcnt(0)" ::: "memory");  // last step: drain
        }
        __builtin_amdgcn_s_barrier();
        // compute step s
        const char* kb = (s & 1) ? (const char*)kbuf1 : (const char*)kbuf0;
        if ((s & 1) == 0) {
            acc0 = (f32x4){0.f, 0.f, 0.f, 0.f};
            acc1 = (f32x4){0.f, 0.f, 0.f, 0.f};
            #pragma unroll
            for (int ds = 0; ds < 8; ++ds) {
                int gA = ds * 4 + lg;
                h16x8 bh = *(const h16x8*)(kb + krow * 512 + ((gA ^ (krow & 7)) << 4));
                h16x8 l0 = *(const h16x8*)((char*)qlbuf + lr * 512 + ((gA ^ (lr & 7)) << 4));
                h16x8 l1 = *(const h16x8*)((char*)qlbuf + (16 + lr) * 512 + ((gA ^ (lr & 7)) << 4));
                acc0 = mfmah(q0h[ds], bh, acc0);
                acc0 = mfmah(l0, bh, acc0);
                acc1 = mfmah(q1h[ds], bh, acc1);
                acc1 = mfmah(l1, bh, acc1);
            }
        } else {
            #pragma unroll
            for (int ds = 0; ds < 8; ++ds) {
                int gA = ds * 4 + lg;
                h16x8 bl = *(const h16x8*)(kb + krow * 512 + ((gA ^ (krow & 7)) << 4));
                acc0 = mfmah(q0h[ds], bl, acc0);
                acc1 = mfmah(q1h[ds], bl, acc1);
            }
            p[s >> 1][0] = acc0;
            p[s >> 1][1] = acc1;
        }
        __builtin_amdgcn_s_barrier();  // all reads of this step's buffer done
    }

    // ---- softmax over k (rows = q), then column sums ----
    #pragma unroll
    for (int c = 0; c < 16; ++c)
        #pragma unroll
        for (int qf = 0; qf < 2; ++qf)
            #pragma unroll
            for (int j = 0; j < 4; ++j) {
                float val = p[c][qf][j] * 0.0625f;   // / sqrt(256)
                p[c][qf][j] = (mv[c] != 0) ? val : NEGINF;
            }
    float mrow[2][4];
    #pragma unroll
    for (int qf = 0; qf < 2; ++qf)
        #pragma unroll
        for (int j = 0; j < 4; ++j) {
            float m = -3.4e38f;
            #pragma unroll
            for (int c = 0; c < 16; ++c) m = fmaxf(m, p[c][qf][j]);
            #pragma unroll
            for (int d = 1; d < 16; d <<= 1) m = fmaxf(m, __shfl_xor(m, d));
            mrow[qf][j] = m;
        }
    if (lr == 0) {
        #pragma unroll
        for (int qf = 0; qf < 2; ++qf)
            #pragma unroll
            for (int j = 0; j < 4; ++j)
                redm[wid * 32 + qf * 16 + lg * 4 + j] = mrow[qf][j];
    }
    __syncthreads();
    float mf[2][4];
    #pragma unroll
    for (int qf = 0; qf < 2; ++qf)
        #pragma unroll
        for (int j = 0; j < 4; ++j) {
            int row = qf * 16 + lg * 4 + j;
            mf[qf][j] = fmaxf(fmaxf(redm[row], redm[32 + row]),
                              fmaxf(redm[64 + row], redm[96 + row]));
        }
    float zp[2][4] = {{0.f,0.f,0.f,0.f},{0.f,0.f,0.f,0.f}};
    #pragma unroll
    for (int c = 0; c < 16; ++c)
        #pragma unroll
        for (int qf = 0; qf < 2; ++qf)
            #pragma unroll
            for (int j = 0; j < 4; ++j) {
                float e = __expf(p[c][qf][j] - mf[qf][j]);
                p[c][qf][j] = e;
                zp[qf][j] += e;
            }
    #pragma unroll
    for (int qf = 0; qf < 2; ++qf)
        #pragma unroll
        for (int j = 0; j < 4; ++j) {
            #pragma unroll
            for (int d = 1; d < 16; d <<= 1) zp[qf][j] += __shfl_xor(zp[qf][j], d);
        }
    if (lr == 0) {
        #pragma unroll
        for (int qf = 0; qf < 2; ++qf)
            #pragma unroll
            for (int j = 0; j < 4; ++j)
                redz[wid * 32 + qf * 16 + lg * 4 + j] = zp[qf][j];
    }
    __syncthreads();
    float rz[2][4];
    #pragma unroll
    for (int qf = 0; qf < 2; ++qf)
        #pragma unroll
        for (int j = 0; j < 4; ++j) {
            int row = qf * 16 + lg * 4 + j;
            float z = redz[row] + redz[32 + row] + redz[64 + row] + redz[96 + row];
            rz[qf][j] = 1.0f / z;
        }
    float* wp = w_part + ((size_t)(b * 32 + qt)) * 1024;
    #pragma unroll
    for (int c = 0; c < 16; ++c) {
        float cs = 0.f;
        #pragma unroll
        for (int qf = 0; qf < 2; ++qf)
            #pragma unroll
            for (int j = 0; j < 4; ++j)
                cs = fmaf(p[c][qf][j], rz[qf][j], cs);
        cs += __shfl_xor(cs, 16);
        cs += __shfl_xor(cs, 32);
        if (lane < 16) wp[c * 64 + wid * 16 + lane] = cs;
    }
}

// ---------------- K3: out[b,d] = (1/S) * sum_k w[b,k] * v[b,k,d] ----------------
__global__ void zero_out_kernel(float* __restrict__ out) {
    out[blockIdx.x * 256 + threadIdx.x] = 0.0f;
}

__global__ __launch_bounds__(256) void pv_kernel(
    const float* __restrict__ w_part, const float* __restrict__ v,
    float* __restrict__ out) {
    __shared__ float wseg[128];
    int t = threadIdx.x;
    int b = blockIdx.x >> 3, ks = blockIdx.x & 7;
    if (t < 128) {
        float s = 0.f;
        #pragma unroll 8
        for (int qt = 0; qt < 32; ++qt)
            s += w_part[((size_t)(b * 32 + qt)) * 1024 + ks * 128 + t];
        wseg[t] = s;
    }
    __syncthreads();
    const float* vb = v + ((size_t)b * 1024 + ks * 128) * ND + t;
    float acc = 0.f;
    #pragma unroll 8
    for (int kk = 0; kk < 128; ++kk)
        acc = fmaf(wseg[kk], vb[(size_t)kk * ND], acc);
    atomicAdd(out + b * 256 + t, acc * (1.0f / 1024.0f));
}

extern "C" void kernel_launch(void* const* d_in, const int* in_sizes, int n_in,
                              void* d_out, int out_size, void* d_ws, size_t ws_size,
                              hipStream_t stream) {
    const float* q = (const float*)d_in[0];
    const float* k = (const float*)d_in[1];
    const float* v = (const float*)d_in[2];
    const int* mask = (const int*)d_in[3];
    const float* W = (const float*)d_in[4];
    char* ws = (char*)d_ws;
    float*    pe  = (float*)ws;                                   // 1 MB
    _Float16* wth = (_Float16*)(ws + 1048576);                    // 128 KB
    _Float16* wtl = (_Float16*)(ws + 1048576 + 131072);           // 128 KB
    _Float16* qph = (_Float16*)(ws + 1310720);                    // 16 MB
    _Float16* qpl = (_Float16*)(ws + 1310720 + 16777216);         // 16 MB
    _Float16* kph = (_Float16*)(ws + 1310720 + 2*16777216);      // 16 MB
    _Float16* kpl = (_Float16*)(ws + 1310720 + 3*16777216);      // 16 MB
    float* wpart  = (float*)(ws + 1310720 + 4*16777216);         // 4 MB
    float* out = (float*)d_out;

    setup_kernel<<<1280, 256, 0, stream>>>(W, pe, wth, wtl);
    proj_kernel<<<1024, 256, 0, stream>>>(q, k, pe, wth, wtl, qph, qpl, kph, kpl);
    attn_kernel<<<1024, 256, 0, stream>>>(qph, qpl, kph, kpl, mask, wpart);
    zero_out_kernel<<<32, 256, 0, stream>>>(out);
    pv_kernel<<<256, 256, 0, stream>>>(wpart, v, out);
}